// Round 3
// baseline (216.977 us; speedup 1.0000x reference)
//
#include <hip/hip_runtime.h>
#include <math.h>

// ws layout (float offsets):
//   cosTM [1024][64]  (fdft basis, [t][m], cos)         @ 0
//   sinTM [1024][64]  (fdft basis, [t][m], MINUS sin)   @ 65536
//   cosMT [64][1088]  (idft basis, [m][t], cos)         @ 131072
//   sinMT [64][1088]  (idft basis, [m][t], plus sin)    @ 200704
//   XP    [tz*4+part (8)][b16] x 65536 ([p2][h8][m64][e64])  @ 270336  (33.5 MB)
//   Y     [b16][p2][x64][ch512]  ch = h*64+e            @ 8658944 (4 MB)
#define COSTM_OFF 0
#define SINTM_OFF 65536
#define COSMT_OFF 131072
#define SINMT_OFF 200704
#define XP_OFF    270336
#define Y_OFF     8658944

__global__ __launch_bounds__(256) void basis_kernel(float* __restrict__ w) {
    int idx = blockIdx.x * 256 + threadIdx.x;
    const float th = 0.0030679615757712823f; // 2*pi/2048
    if (idx < 65536) {
        int t = idx >> 6, m = idx & 63;
        int j = (m * t) & 2047;
        float s, c; sincosf(th * (float)j, &s, &c);
        w[COSTM_OFF + idx] = c;
        w[SINTM_OFF + idx] = -s;   // sign folded: Xi = sum v * (-sin)
    }
    if (idx < 69632) {
        int m = idx / 1088, t = idx - m * 1088;
        int j = (m * t) & 2047;
        float s, c; sincosf(th * (float)j, &s, &c);
        w[COSMT_OFF + idx] = c;
        w[SINMT_OFF + idx] = s;
    }
}

// Forward folded DFT, 8m x 8ch per thread, 64m x 128ch per block, t-quarter per block.
__global__ __launch_bounds__(128, 2) void fdft_kernel(const float* __restrict__ q,
                                                      const float* __restrict__ k,
                                                      float* __restrict__ ws) {
    const int ch0  = blockIdx.x * 128;
    const int b    = blockIdx.y;
    const int tz   = blockIdx.z >> 2;
    const int part = blockIdx.z & 3;
    const float* __restrict__ src   = tz ? k : q;
    const float* __restrict__ cosTM = ws + COSTM_OFF;
    const float* __restrict__ sinTM = ws + SINTM_OFF;
    float* __restrict__ xp = ws + XP_OFF + (size_t)(blockIdx.z * 16 + b) * 65536;

    __shared__ float uL[32][128], vL[32][128];   // 32 KB
    __shared__ float cL[32][64],  sL[32][64];    // 16 KB

    const int tid = threadIdx.x;
    const int m0 = (tid & 7) * 8;       // 8 modes
    const int c0 = (tid >> 3) * 8;      // 8 channels (local, = 1 e x 8 h)

    float ar[8][8] = {{0.f}}, ai[8][8] = {{0.f}};

    const size_t abase = (size_t)b * 2048 * 512 + ch0;
    const int tbeg = part * 256;

    for (int t0 = tbeg; t0 < tbeg + 256; t0 += 32) {
        __syncthreads();
#pragma unroll
        for (int s = 0; s < 8; ++s) {              // 1024 slots: 32 rows x 32 f4
            int slot = tid + s * 128;
            int row = slot >> 5, c4 = slot & 31;
            int t = t0 + row;
            int pr = (t == 0) ? 1024 : (2048 - t);
            float4 av = *(const float4*)(src + abase + (size_t)t  * 512 + c4 * 4);
            float4 pv = *(const float4*)(src + abase + (size_t)pr * 512 + c4 * 4);
            *(float4*)(&uL[row][c4 * 4]) = make_float4(av.x + pv.x, av.y + pv.y, av.z + pv.z, av.w + pv.w);
            *(float4*)(&vL[row][c4 * 4]) = make_float4(av.x - pv.x, av.y - pv.y, av.z - pv.z, av.w - pv.w);
        }
#pragma unroll
        for (int s = 0; s < 4; ++s) {              // 512 slots: 32 rows x 16 f4
            int slot = tid + s * 128;
            int row = slot >> 4, c4 = slot & 15;
            *(float4*)(&cL[row][c4 * 4]) = *(const float4*)(cosTM + (t0 + row) * 64 + c4 * 4);
            *(float4*)(&sL[row][c4 * 4]) = *(const float4*)(sinTM + (t0 + row) * 64 + c4 * 4);
        }
        __syncthreads();
#pragma unroll 4
        for (int tt = 0; tt < 32; ++tt) {
            float cc[8], sv[8], uu[8], vv[8];
            *(float4*)(cc)     = *(const float4*)(&cL[tt][m0]);
            *(float4*)(cc + 4) = *(const float4*)(&cL[tt][m0 + 4]);
            *(float4*)(sv)     = *(const float4*)(&sL[tt][m0]);
            *(float4*)(sv + 4) = *(const float4*)(&sL[tt][m0 + 4]);
            *(float4*)(uu)     = *(const float4*)(&uL[tt][c0]);
            *(float4*)(uu + 4) = *(const float4*)(&uL[tt][c0 + 4]);
            *(float4*)(vv)     = *(const float4*)(&vL[tt][c0]);
            *(float4*)(vv + 4) = *(const float4*)(&vL[tt][c0 + 4]);
#pragma unroll
            for (int im = 0; im < 8; ++im)
#pragma unroll
                for (int ic = 0; ic < 8; ++ic) {
                    ar[im][ic] += cc[im] * uu[ic];
                    ai[im][ic] += sv[im] * vv[ic];
                }
        }
    }
    if (part == 0) {   // odd-m correction: u[0] included a1024 with +1 for all m
        float a10[8];
        *(float4*)(a10)     = *(const float4*)(src + abase + (size_t)1024 * 512 + c0);
        *(float4*)(a10 + 4) = *(const float4*)(src + abase + (size_t)1024 * 512 + c0 + 4);
#pragma unroll
        for (int im = 1; im < 8; im += 2)
#pragma unroll
            for (int ic = 0; ic < 8; ++ic)
                ar[im][ic] -= 2.f * a10[ic];
    }
    // store to XP [p][h][m][e]; this thread's 8 channels = fixed e, h=0..7
    const int e = (ch0 + c0) >> 3;
#pragma unroll
    for (int im = 0; im < 8; ++im)
#pragma unroll
        for (int h = 0; h < 8; ++h) {
            xp[(h * 64 + m0 + im) * 64 + e]         = ar[im][h];
            xp[32768 + (h * 64 + m0 + im) * 64 + e] = ai[im][h];
        }
}

// Middle: per (b,h,x-half). S = Q K (complex, contract e), tanh, xqkv, scale -> Y.
__global__ __launch_bounds__(128) void mid_kernel(float* __restrict__ ws) {
    const int h = blockIdx.x, b = blockIdx.y, xh = blockIdx.z;
    float* __restrict__ Y = ws + Y_OFF + (size_t)b * 65536;

    __shared__ float Qs[2][32][64];   // Q [xl][e]; reused as T [xl][y]
    __shared__ float Ksw[2][64][64];  // K [m][e] XOR-swizzled [m][e^m]

    const int tid = threadIdx.x;
    // stage Q (this x-half), summing 4 t-partials
    for (int slot = tid; slot < 1024; slot += 128) {   // p2 x 32m x 16f4
        int p = slot >> 9, ml = (slot >> 4) & 31, c4 = slot & 15;
        int off = ((p * 8 + h) * 64 + xh * 32 + ml) * 64 + c4 * 4;
        float4 acc = make_float4(0.f, 0.f, 0.f, 0.f);
#pragma unroll
        for (int part = 0; part < 4; ++part) {
            const float4 v = *(const float4*)(ws + XP_OFF + (size_t)(part * 16 + b) * 65536 + off);
            acc.x += v.x; acc.y += v.y; acc.z += v.z; acc.w += v.w;
        }
        *(float4*)(&Qs[p][ml][c4 * 4]) = acc;
    }
    // stage K (full), swizzled
    for (int slot = tid; slot < 2048; slot += 128) {   // p2 x 64m x 16f4
        int p = slot >> 10, ml = (slot >> 4) & 63, c4 = slot & 15;
        int off = ((p * 8 + h) * 64 + ml) * 64 + c4 * 4;
        float4 acc = make_float4(0.f, 0.f, 0.f, 0.f);
#pragma unroll
        for (int part = 0; part < 4; ++part) {
            const float4 v = *(const float4*)(ws + XP_OFF + (size_t)((4 + part) * 16 + b) * 65536 + off);
            acc.x += v.x; acc.y += v.y; acc.z += v.z; acc.w += v.w;
        }
        Ksw[p][ml][(c4 * 4 + 0) ^ ml] = acc.x;
        Ksw[p][ml][(c4 * 4 + 1) ^ ml] = acc.y;
        Ksw[p][ml][(c4 * 4 + 2) ^ ml] = acc.z;
        Ksw[p][ml][(c4 * 4 + 3) ^ ml] = acc.w;
    }
    __syncthreads();

    const int lane = tid & 63;
    const int wid  = tid >> 6;   // 0..1
    const int xb   = wid * 16;

    float sr[16], si[16];
#pragma unroll
    for (int i = 0; i < 16; ++i) { sr[i] = 0.f; si[i] = 0.f; }
    const int y = lane;
    for (int e = 0; e < 64; ++e) {
        float kr = Ksw[0][y][e ^ y];
        float ki = Ksw[1][y][e ^ y];
#pragma unroll
        for (int i = 0; i < 16; ++i) {
            float qr = Qs[0][xb + i][e];
            float qi = Qs[1][xb + i][e];
            sr[i] += qr * kr; sr[i] -= qi * ki;
            si[i] += qr * ki; si[i] += qi * kr;
        }
    }
    float tr[16], ti[16];
#pragma unroll
    for (int i = 0; i < 16; ++i) { tr[i] = tanhf(sr[i]); ti[i] = tanhf(si[i]); }
    __syncthreads();
#pragma unroll
    for (int i = 0; i < 16; ++i) {
        Qs[0][xb + i][y] = tr[i];
        Qs[1][xb + i][y] = ti[i];
    }
    __syncthreads();

    float vr[16], vi[16];
#pragma unroll
    for (int i = 0; i < 16; ++i) { vr[i] = 0.f; vi[i] = 0.f; }
    const int e = lane;
    for (int yy = 0; yy < 64; ++yy) {
        float kr = Ksw[0][yy][e ^ yy];
        float ki = Ksw[1][yy][e ^ yy];
#pragma unroll
        for (int i = 0; i < 16; ++i) {
            float trr = Qs[0][xb + i][yy];
            float tii = Qs[1][xb + i][yy];
            vr[i] += trr * kr; vr[i] -= tii * ki;
            vi[i] += trr * ki; vi[i] += tii * kr;
        }
    }
#pragma unroll
    for (int i = 0; i < 16; ++i) {
        int x = xh * 32 + xb + i;
        float f = (x == 0 ? 1.0f : 2.0f) * (1.0f / (2048.0f * 4096.0f));
        Y[x * 512 + h * 64 + e]         =  f * vr[i];  // Yr
        Y[32768 + x * 512 + h * 64 + e] = -f * vi[i];  // Yi (sign folded)
    }
}

// Inverse folded DFT, 8t x 8ch per thread, 64t x 256ch per block, m in 2 chunks of 32.
// P[t]=sum cos*Yr, Q[t]=sum sin*Yi; out[t]=P+Q (t<=1024), out[2048-t]=P-Q (1<=t<=1023).
__global__ __launch_bounds__(256, 2) void idft_kernel(const float* __restrict__ ws,
                                                      float* __restrict__ out) {
    const int tt0 = blockIdx.x * 64;    // 0..1024 (t up to 1087, masked)
    const int ch0 = blockIdx.y * 256;
    const int b   = blockIdx.z;
    const float* __restrict__ cosMT = ws + COSMT_OFF;
    const float* __restrict__ sinMT = ws + SINMT_OFF;
    const float* __restrict__ Yb = ws + Y_OFF + (size_t)b * 65536;

    __shared__ float bas[2][32][64];    // [cos/sin][ml][tloc]  16 KB
    __shared__ float Ys[2][32][256];    // [p][ml][chloc]       64 KB

    const int tid = threadIdx.x;
    const int tL = (tid & 7) * 8;
    const int cL = (tid >> 3) * 8;

    float P[8][8] = {{0.f}}, Qa[8][8] = {{0.f}};

    for (int mc = 0; mc < 2; ++mc) {
        __syncthreads();
#pragma unroll
        for (int s = 0; s < 4; ++s) {              // 1024 slots: 2tab x 32m x 16f4
            int slot = tid + s * 256;
            int tab = slot >> 9, ml = (slot >> 4) & 31, c4 = slot & 15;
            const float* bsrc = (tab ? sinMT : cosMT) + (mc * 32 + ml) * 1088 + tt0 + c4 * 4;
            *(float4*)(&bas[tab][ml][c4 * 4]) = *(const float4*)bsrc;
        }
#pragma unroll
        for (int s = 0; s < 16; ++s) {             // 4096 slots: 2p x 32m x 64f4
            int slot = tid + s * 256;
            int p = slot >> 11, ml = (slot >> 6) & 31, c4 = slot & 63;
            *(float4*)(&Ys[p][ml][c4 * 4]) =
                *(const float4*)(Yb + p * 32768 + (mc * 32 + ml) * 512 + ch0 + c4 * 4);
        }
        __syncthreads();
#pragma unroll 2
        for (int ml = 0; ml < 32; ++ml) {
            float cc[8], sv[8], rr[8], ii[8];
            *(float4*)(cc)     = *(const float4*)(&bas[0][ml][tL]);
            *(float4*)(cc + 4) = *(const float4*)(&bas[0][ml][tL + 4]);
            *(float4*)(sv)     = *(const float4*)(&bas[1][ml][tL]);
            *(float4*)(sv + 4) = *(const float4*)(&bas[1][ml][tL + 4]);
            *(float4*)(rr)     = *(const float4*)(&Ys[0][ml][cL]);
            *(float4*)(rr + 4) = *(const float4*)(&Ys[0][ml][cL + 4]);
            *(float4*)(ii)     = *(const float4*)(&Ys[1][ml][cL]);
            *(float4*)(ii + 4) = *(const float4*)(&Ys[1][ml][cL + 4]);
#pragma unroll
            for (int it = 0; it < 8; ++it)
#pragma unroll
                for (int ic = 0; ic < 8; ++ic) {
                    P[it][ic]  += cc[it] * rr[ic];
                    Qa[it][ic] += sv[it] * ii[ic];
                }
        }
    }
#pragma unroll
    for (int it = 0; it < 8; ++it) {
        int t = tt0 + tL + it;
        if (t <= 1024) {
            float* op = out + ((size_t)b * 2048 + t) * 512 + ch0 + cL;
            *(float4*)(op)     = make_float4(P[it][0] + Qa[it][0], P[it][1] + Qa[it][1],
                                             P[it][2] + Qa[it][2], P[it][3] + Qa[it][3]);
            *(float4*)(op + 4) = make_float4(P[it][4] + Qa[it][4], P[it][5] + Qa[it][5],
                                             P[it][6] + Qa[it][6], P[it][7] + Qa[it][7]);
        }
        if (t >= 1 && t <= 1023) {
            float* op = out + ((size_t)b * 2048 + (2048 - t)) * 512 + ch0 + cL;
            *(float4*)(op)     = make_float4(P[it][0] - Qa[it][0], P[it][1] - Qa[it][1],
                                             P[it][2] - Qa[it][2], P[it][3] - Qa[it][3]);
            *(float4*)(op + 4) = make_float4(P[it][4] - Qa[it][4], P[it][5] - Qa[it][5],
                                             P[it][6] - Qa[it][6], P[it][7] - Qa[it][7]);
        }
    }
}

extern "C" void kernel_launch(void* const* d_in, const int* in_sizes, int n_in,
                              void* d_out, int out_size, void* d_ws, size_t ws_size,
                              hipStream_t stream) {
    const float* q = (const float*)d_in[0];
    const float* k = (const float*)d_in[1];
    float* ws = (float*)d_ws;      // ~39 MB used
    float* out = (float*)d_out;

    hipLaunchKernelGGL(basis_kernel, dim3(272), dim3(256), 0, stream, ws);
    hipLaunchKernelGGL(fdft_kernel, dim3(4, 16, 8), dim3(128), 0, stream, q, k, ws);
    hipLaunchKernelGGL(mid_kernel, dim3(8, 16, 2), dim3(128), 0, stream, ws);
    hipLaunchKernelGGL(idft_kernel, dim3(17, 2, 16), dim3(256), 0, stream, ws, out);
}

// Round 4
// 215.390 us; speedup vs baseline: 1.0074x; 1.0074x over previous
//
#include <hip/hip_runtime.h>
#include <math.h>

// ws layout (float offsets):
//   cosTM [1024][64]  (fdft basis, [t][m], cos)         @ 0
//   sinTM [1024][64]  (fdft basis, [t][m], MINUS sin)   @ 65536
//   cosMT [64][1088]  (idft basis, [m][t], cos)         @ 131072
//   sinMT [64][1088]  (idft basis, [m][t], plus sin)    @ 200704
//   XP    [z=tz*4+part (8)][b16] x 65536 ([p2][h8][m64][e64]) @ 270336 (33.5 MB)
//   Y     [b16][p2][x64][ch512]  ch = h*64+e            @ 8658944 (4 MB)
#define COSTM_OFF 0
#define SINTM_OFF 65536
#define COSMT_OFF 131072
#define SINMT_OFF 200704
#define XP_OFF    270336
#define Y_OFF     8658944

__global__ __launch_bounds__(256) void basis_kernel(float* __restrict__ w) {
    int idx = blockIdx.x * 256 + threadIdx.x;
    const float th = 0.0030679615757712823f; // 2*pi/2048
    if (idx < 65536) {
        int t = idx >> 6, m = idx & 63;
        int j = (m * t) & 2047;
        float s, c; sincosf(th * (float)j, &s, &c);
        w[COSTM_OFF + idx] = c;
        w[SINTM_OFF + idx] = -s;   // sign folded: Xi = sum v * (-sin)
    }
    if (idx < 69632) {
        int m = idx / 1088, t = idx - m * 1088;
        int j = (m * t) & 2047;
        float s, c; sincosf(th * (float)j, &s, &c);
        w[COSMT_OFF + idx] = c;
        w[SINMT_OFF + idx] = s;
    }
}

// Forward folded DFT, no LDS. Block = 512 thr = 8 waves; wave w -> modes w*8..w*8+7
// (scalar basis loads), lane -> 4 channels (vector data loads). Block covers
// 64m x 256ch, one t-quarter. Xr[m] = sum u[t]cos, Xi[m] = sum v[t](-sin).
__global__ __launch_bounds__(512, 2) void fdft_kernel(const float* __restrict__ q,
                                                      const float* __restrict__ k,
                                                      float* __restrict__ ws) {
    const int chg = blockIdx.x;          // 0..1
    const int b   = blockIdx.y;
    const int z   = blockIdx.z;          // tz*4 + part
    const int part = z & 3;
    const float* __restrict__ src   = (z >> 2) ? k : q;
    const float* __restrict__ cosTM = ws + COSTM_OFF;
    const float* __restrict__ sinTM = ws + SINTM_OFF;
    float* __restrict__ xp = ws + XP_OFF + (size_t)(z * 16 + b) * 65536;

    const int tid  = threadIdx.x;
    const int lane = tid & 63;
    const int w    = __builtin_amdgcn_readfirstlane(tid >> 6);
    const int m0   = w * 8;
    const int ch0  = chg * 256 + lane * 4;

    float ar[8][4] = {{0.f}}, ai[8][4] = {{0.f}};
    const float* __restrict__ ap = src + (size_t)b * 2048 * 512 + ch0;

    int tbeg = part * 256;
    if (part == 0) {
        // t = 0 peeled: cos=1, sin=0; u[0] = a0 + a1024, and odd m flip a1024 sign.
        float4 a0 = *(const float4*)(ap);
        float4 a1 = *(const float4*)(ap + (size_t)1024 * 512);
        const float ue[4] = {a0.x + a1.x, a0.y + a1.y, a0.z + a1.z, a0.w + a1.w};
        const float uo[4] = {a0.x - a1.x, a0.y - a1.y, a0.z - a1.z, a0.w - a1.w};
#pragma unroll
        for (int im = 0; im < 8; ++im)
#pragma unroll
            for (int ic = 0; ic < 4; ++ic)
                ar[im][ic] += (im & 1) ? uo[ic] : ue[ic];
        tbeg = 1;
    }
    const int tend = (part * 256) + 256;

    for (int t = tbeg; t < tend; ++t) {
        const float4 av = *(const float4*)(ap + (size_t)t * 512);
        const float4 pv = *(const float4*)(ap + (size_t)(2048 - t) * 512);
        const float uu[4] = {av.x + pv.x, av.y + pv.y, av.z + pv.z, av.w + pv.w};
        const float vv[4] = {av.x - pv.x, av.y - pv.y, av.z - pv.z, av.w - pv.w};
        const float* __restrict__ cb = cosTM + t * 64 + m0;   // wave-uniform -> s_load
        const float* __restrict__ sb = sinTM + t * 64 + m0;
        float cc[8], sv[8];
#pragma unroll
        for (int i = 0; i < 8; ++i) { cc[i] = cb[i]; sv[i] = sb[i]; }
#pragma unroll
        for (int im = 0; im < 8; ++im)
#pragma unroll
            for (int ic = 0; ic < 4; ++ic) {
                ar[im][ic] += cc[im] * uu[ic];
                ai[im][ic] += sv[im] * vv[ic];
            }
    }

    // store to XP [p][h][m][e]; thread's 4 channels: ch = ch0+ic, h = ch&7, e = ch>>3
#pragma unroll
    for (int im = 0; im < 8; ++im)
#pragma unroll
        for (int ic = 0; ic < 4; ++ic) {
            const int ch = ch0 + ic, h = ch & 7, e = ch >> 3;
            xp[(h * 64 + m0 + im) * 64 + e]         = ar[im][ic];
            xp[32768 + (h * 64 + m0 + im) * 64 + e] = ai[im][ic];
        }
}

// Middle: per (b,h,x-half). S = Q K (complex, contract e), tanh, xqkv, scale -> Y.
__global__ __launch_bounds__(128) void mid_kernel(float* __restrict__ ws) {
    const int h = blockIdx.x, b = blockIdx.y, xh = blockIdx.z;
    float* __restrict__ Y = ws + Y_OFF + (size_t)b * 65536;

    __shared__ float Qs[2][32][64];   // Q [xl][e]; reused as T [xl][y]
    __shared__ float Ksw[2][64][64];  // K [m][e] XOR-swizzled [m][e^m]

    const int tid = threadIdx.x;
    for (int slot = tid; slot < 1024; slot += 128) {   // p2 x 32m x 16f4
        int p = slot >> 9, ml = (slot >> 4) & 31, c4 = slot & 15;
        int off = ((p * 8 + h) * 64 + xh * 32 + ml) * 64 + c4 * 4;
        float4 acc = make_float4(0.f, 0.f, 0.f, 0.f);
#pragma unroll
        for (int part = 0; part < 4; ++part) {
            const float4 v = *(const float4*)(ws + XP_OFF + (size_t)(part * 16 + b) * 65536 + off);
            acc.x += v.x; acc.y += v.y; acc.z += v.z; acc.w += v.w;
        }
        *(float4*)(&Qs[p][ml][c4 * 4]) = acc;
    }
    for (int slot = tid; slot < 2048; slot += 128) {   // p2 x 64m x 16f4
        int p = slot >> 10, ml = (slot >> 4) & 63, c4 = slot & 15;
        int off = ((p * 8 + h) * 64 + ml) * 64 + c4 * 4;
        float4 acc = make_float4(0.f, 0.f, 0.f, 0.f);
#pragma unroll
        for (int part = 0; part < 4; ++part) {
            const float4 v = *(const float4*)(ws + XP_OFF + (size_t)((4 + part) * 16 + b) * 65536 + off);
            acc.x += v.x; acc.y += v.y; acc.z += v.z; acc.w += v.w;
        }
        Ksw[p][ml][(c4 * 4 + 0) ^ ml] = acc.x;
        Ksw[p][ml][(c4 * 4 + 1) ^ ml] = acc.y;
        Ksw[p][ml][(c4 * 4 + 2) ^ ml] = acc.z;
        Ksw[p][ml][(c4 * 4 + 3) ^ ml] = acc.w;
    }
    __syncthreads();

    const int lane = tid & 63;
    const int wid  = tid >> 6;   // 0..1
    const int xb   = wid * 16;

    float sr[16], si[16];
#pragma unroll
    for (int i = 0; i < 16; ++i) { sr[i] = 0.f; si[i] = 0.f; }
    const int y = lane;
    for (int e = 0; e < 64; ++e) {
        float kr = Ksw[0][y][e ^ y];
        float ki = Ksw[1][y][e ^ y];
#pragma unroll
        for (int i = 0; i < 16; ++i) {
            float qr = Qs[0][xb + i][e];
            float qi = Qs[1][xb + i][e];
            sr[i] += qr * kr; sr[i] -= qi * ki;
            si[i] += qr * ki; si[i] += qi * kr;
        }
    }
    float tr[16], ti[16];
#pragma unroll
    for (int i = 0; i < 16; ++i) { tr[i] = tanhf(sr[i]); ti[i] = tanhf(si[i]); }
    __syncthreads();
#pragma unroll
    for (int i = 0; i < 16; ++i) {
        Qs[0][xb + i][y] = tr[i];
        Qs[1][xb + i][y] = ti[i];
    }
    __syncthreads();

    float vr[16], vi[16];
#pragma unroll
    for (int i = 0; i < 16; ++i) { vr[i] = 0.f; vi[i] = 0.f; }
    const int e = lane;
    for (int yy = 0; yy < 64; ++yy) {
        float kr = Ksw[0][yy][e ^ yy];
        float ki = Ksw[1][yy][e ^ yy];
#pragma unroll
        for (int i = 0; i < 16; ++i) {
            float trr = Qs[0][xb + i][yy];
            float tii = Qs[1][xb + i][yy];
            vr[i] += trr * kr; vr[i] -= tii * ki;
            vi[i] += trr * ki; vi[i] += tii * kr;
        }
    }
#pragma unroll
    for (int i = 0; i < 16; ++i) {
        int x = xh * 32 + xb + i;
        float f = (x == 0 ? 1.0f : 2.0f) * (1.0f / (2048.0f * 4096.0f));
        Y[x * 512 + h * 64 + e]         =  f * vr[i];  // Yr
        Y[32768 + x * 512 + h * 64 + e] = -f * vi[i];  // Yi (sign folded)
    }
}

// Inverse folded DFT, no LDS. Block = 512 thr = 8 waves; wave w -> 8 t-values
// (scalar basis), lane -> 4 channels. P[t]=sum cos*Yr, Q[t]=sum sin*Yi;
// out[t]=P+Q (t<=1024), out[2048-t]=P-Q (1<=t<=1023).
__global__ __launch_bounds__(512, 2) void idft_kernel(const float* __restrict__ ws,
                                                      float* __restrict__ out) {
    const int tt0 = blockIdx.x * 64;    // t tile base (up to 1087, masked on store)
    const int chg = blockIdx.y;         // 0..1
    const int b   = blockIdx.z;
    const float* __restrict__ cosMT = ws + COSMT_OFF;
    const float* __restrict__ sinMT = ws + SINMT_OFF;
    const float* __restrict__ Yb = ws + Y_OFF + (size_t)b * 65536;

    const int tid  = threadIdx.x;
    const int lane = tid & 63;
    const int w    = __builtin_amdgcn_readfirstlane(tid >> 6);
    const int tb   = tt0 + w * 8;
    const int ch0  = chg * 256 + lane * 4;

    float P[8][4] = {{0.f}}, Qa[8][4] = {{0.f}};

    for (int m = 0; m < 64; ++m) {
        const float4 yr = *(const float4*)(Yb + m * 512 + ch0);
        const float4 yi = *(const float4*)(Yb + 32768 + m * 512 + ch0);
        const float rr[4] = {yr.x, yr.y, yr.z, yr.w};
        const float ii[4] = {yi.x, yi.y, yi.z, yi.w};
        const float* __restrict__ cb = cosMT + m * 1088 + tb;   // wave-uniform -> s_load
        const float* __restrict__ sb = sinMT + m * 1088 + tb;
        float cc[8], sv[8];
#pragma unroll
        for (int i = 0; i < 8; ++i) { cc[i] = cb[i]; sv[i] = sb[i]; }
#pragma unroll
        for (int it = 0; it < 8; ++it)
#pragma unroll
            for (int ic = 0; ic < 4; ++ic) {
                P[it][ic]  += cc[it] * rr[ic];
                Qa[it][ic] += sv[it] * ii[ic];
            }
    }

#pragma unroll
    for (int it = 0; it < 8; ++it) {
        const int t = tb + it;
        if (t <= 1024) {
            *(float4*)(out + ((size_t)b * 2048 + t) * 512 + ch0) =
                make_float4(P[it][0] + Qa[it][0], P[it][1] + Qa[it][1],
                            P[it][2] + Qa[it][2], P[it][3] + Qa[it][3]);
        }
        if (t >= 1 && t <= 1023) {
            *(float4*)(out + ((size_t)b * 2048 + (2048 - t)) * 512 + ch0) =
                make_float4(P[it][0] - Qa[it][0], P[it][1] - Qa[it][1],
                            P[it][2] - Qa[it][2], P[it][3] - Qa[it][3]);
        }
    }
}

extern "C" void kernel_launch(void* const* d_in, const int* in_sizes, int n_in,
                              void* d_out, int out_size, void* d_ws, size_t ws_size,
                              hipStream_t stream) {
    const float* q = (const float*)d_in[0];
    const float* k = (const float*)d_in[1];
    float* ws = (float*)d_ws;      // ~39 MB used
    float* out = (float*)d_out;

    hipLaunchKernelGGL(basis_kernel, dim3(272), dim3(256), 0, stream, ws);
    hipLaunchKernelGGL(fdft_kernel, dim3(2, 16, 8), dim3(512), 0, stream, q, k, ws);
    hipLaunchKernelGGL(mid_kernel, dim3(8, 16, 2), dim3(128), 0, stream, ws);
    hipLaunchKernelGGL(idft_kernel, dim3(17, 2, 16), dim3(512), 0, stream, ws, out);
}

// Round 5
// 152.918 us; speedup vs baseline: 1.4189x; 1.4085x over previous
//
#include <hip/hip_runtime.h>
#include <math.h>

// ws layout (float offsets):
//   cosTM [1024][64]  (fdft basis, [t][m], cos)         @ 0
//   sinTM [1024][64]  (fdft basis, [t][m], MINUS sin)   @ 65536
//   cosMT [64][1088]  (idft basis, [m][t], cos)         @ 131072
//   sinMT [64][1088]  (idft basis, [m][t], plus sin)    @ 200704
//   XP    [z=tz*4+part (8)][b16] x 65536 ([p2][h8][m64][e64]) @ 270336 (33.5 MB)
//   Y     [b16][p2][x64][ch512]  ch = h*64+e            @ 8658944 (4 MB)
#define COSTM_OFF 0
#define SINTM_OFF 65536
#define COSMT_OFF 131072
#define SINMT_OFF 200704
#define XP_OFF    270336
#define Y_OFF     8658944

__global__ __launch_bounds__(256) void basis_kernel(float* __restrict__ w) {
    int idx = blockIdx.x * 256 + threadIdx.x;
    const float th = 0.0030679615757712823f; // 2*pi/2048
    if (idx < 65536) {
        int t = idx >> 6, m = idx & 63;
        int j = (m * t) & 2047;
        float s, c; sincosf(th * (float)j, &s, &c);
        w[COSTM_OFF + idx] = c;
        w[SINTM_OFF + idx] = -s;   // sign folded: Xi = sum v * (-sin)
    }
    if (idx < 69632) {
        int m = idx / 1088, t = idx - m * 1088;
        int j = (m * t) & 2047;
        float s, c; sincosf(th * (float)j, &s, &c);
        w[COSMT_OFF + idx] = c;
        w[SINMT_OFF + idx] = s;
    }
}

// Forward folded DFT. Block 256 thr = 4 waves. Wave wy -> 8 modes (m0 =
// mgrp*32 + wy*8, wave-uniform -> s_load basis). lane -> 4 channels from
// LDS-staged u,v rows (staged once per block -> no cross-wave redundancy).
// Block covers 32m x 256ch, one t-quarter. Grid (chgrp2, b16, tz2*part4*mgrp2).
__global__ __launch_bounds__(256, 2) void fdft_kernel(const float* __restrict__ q,
                                                      const float* __restrict__ k,
                                                      float* __restrict__ ws) {
    const int chgrp = blockIdx.x;
    const int b     = blockIdx.y;
    const int z     = blockIdx.z;
    const int tz = z >> 3, part = (z >> 1) & 3, mgrp = z & 1;
    const float* __restrict__ src   = tz ? k : q;
    const float* __restrict__ cosTM = ws + COSTM_OFF;
    const float* __restrict__ sinTM = ws + SINTM_OFF;
    float* __restrict__ xp = ws + XP_OFF + (size_t)((tz * 4 + part) * 16 + b) * 65536;

    __shared__ float uS[8][256], vS[8][256];   // 16 KB

    const int tid  = threadIdx.x;
    const int lane = tid & 63;
    const int m0   = __builtin_amdgcn_readfirstlane(mgrp * 32 + (tid >> 6) * 8);
    const int ch0  = chgrp * 256 + lane * 4;

    float ar[8][4] = {{0.f}}, ai[8][4] = {{0.f}};
    const size_t bbase = (size_t)b * 2048 * 512;

    const int tbeg = part * 256;
    for (int t0 = tbeg; t0 < tbeg + 256; t0 += 8) {
        __syncthreads();
#pragma unroll
        for (int s = 0; s < 2; ++s) {          // 512 f4 slots: 8 rows x 64 f4
            int slot = tid + s * 256;
            int row = slot >> 6, c4 = slot & 63;
            int t = t0 + row;
            int pr = (t == 0) ? 1024 : (2048 - t);
            const float4 av = *(const float4*)(src + bbase + (size_t)t  * 512 + chgrp * 256 + c4 * 4);
            const float4 pv = *(const float4*)(src + bbase + (size_t)pr * 512 + chgrp * 256 + c4 * 4);
            *(float4*)(&uS[row][c4 * 4]) = make_float4(av.x + pv.x, av.y + pv.y, av.z + pv.z, av.w + pv.w);
            *(float4*)(&vS[row][c4 * 4]) = make_float4(av.x - pv.x, av.y - pv.y, av.z - pv.z, av.w - pv.w);
        }
        __syncthreads();
#pragma unroll
        for (int tt = 0; tt < 8; ++tt) {
            const int t = t0 + tt;
            const float* __restrict__ cb = cosTM + t * 64 + m0;   // wave-uniform -> s_load
            const float* __restrict__ sb = sinTM + t * 64 + m0;
            float cc[8], sv[8];
#pragma unroll
            for (int i = 0; i < 8; ++i) { cc[i] = cb[i]; sv[i] = sb[i]; }
            const float4 u4 = *(const float4*)(&uS[tt][lane * 4]);
            const float4 v4 = *(const float4*)(&vS[tt][lane * 4]);
            const float uu[4] = {u4.x, u4.y, u4.z, u4.w};
            const float vv[4] = {v4.x, v4.y, v4.z, v4.w};
#pragma unroll
            for (int im = 0; im < 8; ++im)
#pragma unroll
                for (int ic = 0; ic < 4; ++ic) {
                    ar[im][ic] += cc[im] * uu[ic];
                    ai[im][ic] += sv[im] * vv[ic];
                }
        }
    }
    if (part == 0) {   // odd-m correction: t=0 staged u included a1024 with +1 for all m
        const float4 a1 = *(const float4*)(src + bbase + (size_t)1024 * 512 + ch0);
        const float aa[4] = {a1.x, a1.y, a1.z, a1.w};
#pragma unroll
        for (int im = 1; im < 8; im += 2)
#pragma unroll
            for (int ic = 0; ic < 4; ++ic)
                ar[im][ic] -= 2.f * aa[ic];
    }
    // store to XP [p][h][m][e]; thread's 4 channels: ch = ch0+ic, h = ch&7, e = ch>>3
#pragma unroll
    for (int im = 0; im < 8; ++im)
#pragma unroll
        for (int ic = 0; ic < 4; ++ic) {
            const int ch = ch0 + ic, h = ch & 7, e = ch >> 3;
            xp[(h * 64 + m0 + im) * 64 + e]         = ar[im][ic];
            xp[32768 + (h * 64 + m0 + im) * 64 + e] = ai[im][ic];
        }
}

// Middle: per (b,h,x-half). S = Q K (complex, contract e), tanh, xqkv, scale -> Y.
__global__ __launch_bounds__(128) void mid_kernel(float* __restrict__ ws) {
    const int h = blockIdx.x, b = blockIdx.y, xh = blockIdx.z;
    float* __restrict__ Y = ws + Y_OFF + (size_t)b * 65536;

    __shared__ float Qs[2][32][64];   // Q [xl][e]; reused as T [xl][y]
    __shared__ float Ksw[2][64][64];  // K [m][e] XOR-swizzled [m][e^m]

    const int tid = threadIdx.x;
    for (int slot = tid; slot < 1024; slot += 128) {   // p2 x 32m x 16f4
        int p = slot >> 9, ml = (slot >> 4) & 31, c4 = slot & 15;
        int off = ((p * 8 + h) * 64 + xh * 32 + ml) * 64 + c4 * 4;
        float4 acc = make_float4(0.f, 0.f, 0.f, 0.f);
#pragma unroll
        for (int part = 0; part < 4; ++part) {
            const float4 v = *(const float4*)(ws + XP_OFF + (size_t)(part * 16 + b) * 65536 + off);
            acc.x += v.x; acc.y += v.y; acc.z += v.z; acc.w += v.w;
        }
        *(float4*)(&Qs[p][ml][c4 * 4]) = acc;
    }
    for (int slot = tid; slot < 2048; slot += 128) {   // p2 x 64m x 16f4
        int p = slot >> 10, ml = (slot >> 4) & 63, c4 = slot & 15;
        int off = ((p * 8 + h) * 64 + ml) * 64 + c4 * 4;
        float4 acc = make_float4(0.f, 0.f, 0.f, 0.f);
#pragma unroll
        for (int part = 0; part < 4; ++part) {
            const float4 v = *(const float4*)(ws + XP_OFF + (size_t)((4 + part) * 16 + b) * 65536 + off);
            acc.x += v.x; acc.y += v.y; acc.z += v.z; acc.w += v.w;
        }
        Ksw[p][ml][(c4 * 4 + 0) ^ ml] = acc.x;
        Ksw[p][ml][(c4 * 4 + 1) ^ ml] = acc.y;
        Ksw[p][ml][(c4 * 4 + 2) ^ ml] = acc.z;
        Ksw[p][ml][(c4 * 4 + 3) ^ ml] = acc.w;
    }
    __syncthreads();

    const int lane = tid & 63;
    const int wid  = tid >> 6;   // 0..1
    const int xb   = wid * 16;

    float sr[16], si[16];
#pragma unroll
    for (int i = 0; i < 16; ++i) { sr[i] = 0.f; si[i] = 0.f; }
    const int y = lane;
    for (int e = 0; e < 64; ++e) {
        float kr = Ksw[0][y][e ^ y];
        float ki = Ksw[1][y][e ^ y];
#pragma unroll
        for (int i = 0; i < 16; ++i) {
            float qr = Qs[0][xb + i][e];
            float qi = Qs[1][xb + i][e];
            sr[i] += qr * kr; sr[i] -= qi * ki;
            si[i] += qr * ki; si[i] += qi * kr;
        }
    }
    float tr[16], ti[16];
#pragma unroll
    for (int i = 0; i < 16; ++i) { tr[i] = tanhf(sr[i]); ti[i] = tanhf(si[i]); }
    __syncthreads();
#pragma unroll
    for (int i = 0; i < 16; ++i) {
        Qs[0][xb + i][y] = tr[i];
        Qs[1][xb + i][y] = ti[i];
    }
    __syncthreads();

    float vr[16], vi[16];
#pragma unroll
    for (int i = 0; i < 16; ++i) { vr[i] = 0.f; vi[i] = 0.f; }
    const int e = lane;
    for (int yy = 0; yy < 64; ++yy) {
        float kr = Ksw[0][yy][e ^ yy];
        float ki = Ksw[1][yy][e ^ yy];
#pragma unroll
        for (int i = 0; i < 16; ++i) {
            float trr = Qs[0][xb + i][yy];
            float tii = Qs[1][xb + i][yy];
            vr[i] += trr * kr; vr[i] -= tii * ki;
            vi[i] += trr * ki; vi[i] += tii * kr;
        }
    }
#pragma unroll
    for (int i = 0; i < 16; ++i) {
        int x = xh * 32 + xb + i;
        float f = (x == 0 ? 1.0f : 2.0f) * (1.0f / (2048.0f * 4096.0f));
        Y[x * 512 + h * 64 + e]         =  f * vr[i];  // Yr
        Y[32768 + x * 512 + h * 64 + e] = -f * vi[i];  // Yi (sign folded)
    }
}

// Inverse folded DFT. Block 256 thr = 4 waves. Wave wy -> 8 t-values
// (wave-uniform -> s_load basis), lane -> 4 channels from LDS-staged Y
// (m in 4 chunks of 16). Block covers 32t x 256ch.
// P[t]=sum cos*Yr, Q[t]=sum sin*Yi; out[t]=P+Q (t<=1024), out[2048-t]=P-Q.
__global__ __launch_bounds__(256, 2) void idft_kernel(const float* __restrict__ ws,
                                                      float* __restrict__ out) {
    const int tt0   = blockIdx.x * 32;   // up to 1087, masked on store
    const int chgrp = blockIdx.y;
    const int b     = blockIdx.z;
    const float* __restrict__ cosMT = ws + COSMT_OFF;
    const float* __restrict__ sinMT = ws + SINMT_OFF;
    const float* __restrict__ Yb = ws + Y_OFF + (size_t)b * 65536;

    __shared__ float yrS[16][256], yiS[16][256];   // 32 KB

    const int tid  = threadIdx.x;
    const int lane = tid & 63;
    const int tb   = tt0 + __builtin_amdgcn_readfirstlane((tid >> 6) * 8);
    const int ch0  = chgrp * 256 + lane * 4;

    float P[8][4] = {{0.f}}, Qa[8][4] = {{0.f}};

    for (int mc = 0; mc < 4; ++mc) {
        __syncthreads();
#pragma unroll
        for (int s = 0; s < 4; ++s) {          // Yr: 1024 f4 slots = 16m x 64 f4
            int slot = tid + s * 256;
            int ml = slot >> 6, c4 = slot & 63;
            *(float4*)(&yrS[ml][c4 * 4]) =
                *(const float4*)(Yb + (mc * 16 + ml) * 512 + chgrp * 256 + c4 * 4);
        }
#pragma unroll
        for (int s = 0; s < 4; ++s) {          // Yi
            int slot = tid + s * 256;
            int ml = slot >> 6, c4 = slot & 63;
            *(float4*)(&yiS[ml][c4 * 4]) =
                *(const float4*)(Yb + 32768 + (mc * 16 + ml) * 512 + chgrp * 256 + c4 * 4);
        }
        __syncthreads();
#pragma unroll 4
        for (int ml = 0; ml < 16; ++ml) {
            const int m = mc * 16 + ml;
            const float* __restrict__ cb = cosMT + m * 1088 + tb;   // wave-uniform -> s_load
            const float* __restrict__ sb = sinMT + m * 1088 + tb;
            float cc[8], sv[8];
#pragma unroll
            for (int i = 0; i < 8; ++i) { cc[i] = cb[i]; sv[i] = sb[i]; }
            const float4 yr = *(const float4*)(&yrS[ml][lane * 4]);
            const float4 yi = *(const float4*)(&yiS[ml][lane * 4]);
            const float rr[4] = {yr.x, yr.y, yr.z, yr.w};
            const float ii[4] = {yi.x, yi.y, yi.z, yi.w};
#pragma unroll
            for (int it = 0; it < 8; ++it)
#pragma unroll
                for (int ic = 0; ic < 4; ++ic) {
                    P[it][ic]  += cc[it] * rr[ic];
                    Qa[it][ic] += sv[it] * ii[ic];
                }
        }
    }

#pragma unroll
    for (int it = 0; it < 8; ++it) {
        const int t = tb + it;
        if (t <= 1024) {
            *(float4*)(out + ((size_t)b * 2048 + t) * 512 + ch0) =
                make_float4(P[it][0] + Qa[it][0], P[it][1] + Qa[it][1],
                            P[it][2] + Qa[it][2], P[it][3] + Qa[it][3]);
        }
        if (t >= 1 && t <= 1023) {
            *(float4*)(out + ((size_t)b * 2048 + (2048 - t)) * 512 + ch0) =
                make_float4(P[it][0] - Qa[it][0], P[it][1] - Qa[it][1],
                            P[it][2] - Qa[it][2], P[it][3] - Qa[it][3]);
        }
    }
}

extern "C" void kernel_launch(void* const* d_in, const int* in_sizes, int n_in,
                              void* d_out, int out_size, void* d_ws, size_t ws_size,
                              hipStream_t stream) {
    const float* q = (const float*)d_in[0];
    const float* k = (const float*)d_in[1];
    float* ws = (float*)d_ws;      // ~39 MB used
    float* out = (float*)d_out;

    hipLaunchKernelGGL(basis_kernel, dim3(272), dim3(256), 0, stream, ws);
    hipLaunchKernelGGL(fdft_kernel, dim3(2, 16, 16), dim3(256), 0, stream, q, k, ws);
    hipLaunchKernelGGL(mid_kernel, dim3(8, 16, 2), dim3(128), 0, stream, ws);
    hipLaunchKernelGGL(idft_kernel, dim3(34, 2, 16), dim3(256), 0, stream, ws, out);
}